// Round 27
// baseline (265.460 us; speedup 1.0000x reference)
//
#include <hip/hip_runtime.h>
#include <hip/hip_bf16.h>

typedef __attribute__((ext_vector_type(8))) __bf16 bf16x8;
typedef __attribute__((ext_vector_type(4))) float f32x4;

#define DEVI static __device__ __forceinline__

// ---- helpers ---------------------------------------------------------------

DEVI ushort f2bf(float f) {
  unsigned u = __builtin_bit_cast(unsigned, f);
  return (ushort)((u + 0x7fffu + ((u >> 16) & 1u)) >> 16);
}

union BF8 { unsigned u[4]; bf16x8 v; };

DEVI bf16x8 cvt8(const float* __restrict__ p) {
  const f32x4 a = *(const f32x4*)p;
  const f32x4 b = *(const f32x4*)(p + 4);
  BF8 r;
  asm("v_cvt_pk_bf16_f32 %0, %1, %2" : "=v"(r.u[0]) : "v"(a.x), "v"(a.y));
  asm("v_cvt_pk_bf16_f32 %0, %1, %2" : "=v"(r.u[1]) : "v"(a.z), "v"(a.w));
  asm("v_cvt_pk_bf16_f32 %0, %1, %2" : "=v"(r.u[2]) : "v"(b.x), "v"(b.y));
  asm("v_cvt_pk_bf16_f32 %0, %1, %2" : "=v"(r.u[3]) : "v"(b.z), "v"(b.w));
  return r.v;
}

DEVI bf16x8 cvt8r(f32x4 a, f32x4 b) {
  BF8 r;
  asm("v_cvt_pk_bf16_f32 %0, %1, %2" : "=v"(r.u[0]) : "v"(a.x), "v"(a.y));
  asm("v_cvt_pk_bf16_f32 %0, %1, %2" : "=v"(r.u[1]) : "v"(a.z), "v"(a.w));
  asm("v_cvt_pk_bf16_f32 %0, %1, %2" : "=v"(r.u[2]) : "v"(b.x), "v"(b.y));
  asm("v_cvt_pk_bf16_f32 %0, %1, %2" : "=v"(r.u[3]) : "v"(b.z), "v"(b.w));
  return r.v;
}

DEVI unsigned cvtpk1(float lo, float hi) {
  unsigned r;
  asm("v_cvt_pk_bf16_f32 %0, %1, %2" : "=v"(r) : "v"(lo), "v"(hi));
  return r;
}

DEVI void gload16(const void* g, void* l) {
  __builtin_amdgcn_global_load_lds(
      (const __attribute__((address_space(1))) unsigned*)g,
      (__attribute__((address_space(3))) unsigned*)l, 16, 0, 0);
}

DEVI int xcd_swizzle(int bid, int nwg) {
  return (bid & 7) * (nwg >> 3) + (bid >> 3);
}

DEVI f32x4 mfma16(bf16x8 a, bf16x8 b, f32x4 c) {
  return __builtin_amdgcn_mfma_f32_16x16x32_bf16(a, b, c, 0, 0, 0);
}

// ---- weight convert --------------------------------------------------------

__global__ __launch_bounds__(256) void cvt_w(
    const float* __restrict__ wq, const float* __restrict__ wk,
    const float* __restrict__ wv, const float* __restrict__ wo,
    ushort* __restrict__ oq, ushort* __restrict__ ok2,
    ushort* __restrict__ ov, ushort* __restrict__ oo) {
  const int s = blockIdx.x >> 7;
  const int tb = blockIdx.x & 127;
  const float* src = s == 0 ? wq : (s == 1 ? wk : (s == 2 ? wv : wo));
  ushort* dst = s == 0 ? oq : (s == 1 ? ok2 : (s == 2 ? ov : oo));
  const unsigned G = 128 * 256;
  const unsigned t = tb * 256 + threadIdx.x;
#pragma unroll
  for (int j = 0; j < 4; ++j) {
    const size_t i = (size_t)t + (size_t)j * G;
    *(bf16x8*)(dst + i * 8) = cvt8(src + i * 8);
  }
}

// ---- GEMM (bf16 A): 256x256 tile, BK=32, fine-phase (final projection) -----

template <int OUT>
__global__ __launch_bounds__(512, 2) void gemm_8ph(
    const ushort* __restrict__ A, const ushort* __restrict__ B,
    const float* __restrict__ bias, void* __restrict__ Cp, int N, int K) {
  __shared__ __align__(16) ushort Asm[4][8192];
  __shared__ __align__(16) ushort Bsm[4][8192];
  const int tid = threadIdx.x, lane = tid & 63;
  const int wv = tid >> 6;
  const int wr = wv >> 2, wc = wv & 3;
  const int cc = lane & 15, cr = lane >> 4;
  const int nw = N >> 8;
  const int work = xcd_swizzle(blockIdx.x, gridDim.x);
  const size_t m0 = (size_t)(work / nw) * 256;
  const size_t n0 = (size_t)(work % nw) * 256;

  const ushort *ag[2], *bg[2];
#pragma unroll
  for (int h = 0; h < 2; ++h) {
    const int u = tid + h * 512;
    const int row = u >> 2, slot = u & 3;
    const int gc = (slot ^ ((row >> 1) & 3)) * 8;
    ag[h] = A + (m0 + row) * (size_t)K + gc;
    bg[h] = B + (n0 + row) * (size_t)K + gc;
  }

  auto stageh = [&](int buf, int kt, int h) {
    gload16(ag[h] + kt, &Asm[buf][(tid + h * 512) * 8]);
    gload16(bg[h] + kt, &Bsm[buf][(tid + h * 512) * 8]);
  };

  f32x4 acc[8][4] = {};
  const int nt = K >> 5;

  int aoff[8], boff[4];
#pragma unroll
  for (int m = 0; m < 8; ++m) {
    const int row = wr * 128 + m * 16 + cc;
    aoff[m] = (row * 4 + (cr ^ ((row >> 1) & 3))) * 8;
  }
#pragma unroll
  for (int n = 0; n < 4; ++n) {
    const int row = wc * 64 + n * 16 + cc;
    boff[n] = (row * 4 + (cr ^ ((row >> 1) & 3))) * 8;
  }

#pragma unroll
  for (int p = 0; p < 3; ++p) {
    stageh(p, p << 5, 0);
    stageh(p, p << 5, 1);
  }
  asm volatile("s_waitcnt vmcnt(8)" ::: "memory");
  __builtin_amdgcn_s_barrier();
  asm volatile("" ::: "memory");

  for (int k = 0; k < nt; ++k) {
    const ushort* Ab = Asm[k & 3];
    const ushort* Bb = Bsm[k & 3];
    const int wb = (k + 3) & 3;
    const bool more = (k + 3 < nt);
    bf16x8 bf[4], af[4];

#pragma unroll
    for (int n = 0; n < 4; ++n) bf[n] = *(const bf16x8*)&Bb[boff[n]];
#pragma unroll
    for (int m = 0; m < 4; ++m) af[m] = *(const bf16x8*)&Ab[aoff[m]];
    if (more) stageh(wb, (k + 3) << 5, 0);
    __builtin_amdgcn_s_barrier();
    asm volatile("s_waitcnt lgkmcnt(0)" ::: "memory");
    __builtin_amdgcn_s_setprio(1);
#pragma unroll
    for (int m = 0; m < 4; ++m)
#pragma unroll
      for (int n = 0; n < 4; ++n)
        acc[m][n] = mfma16(af[m], bf[n], acc[m][n]);
    __builtin_amdgcn_s_setprio(0);
    asm volatile("" ::: "memory");
    __builtin_amdgcn_s_barrier();

#pragma unroll
    for (int m = 0; m < 4; ++m) af[m] = *(const bf16x8*)&Ab[aoff[4 + m]];
    if (more) stageh(wb, (k + 3) << 5, 1);
    if (k < nt - 3) {
      asm volatile("s_waitcnt vmcnt(8)" ::: "memory");
    } else if (k == nt - 3) {
      asm volatile("s_waitcnt vmcnt(4)" ::: "memory");
    } else if (k == nt - 2) {
      asm volatile("s_waitcnt vmcnt(0)" ::: "memory");
    }
    __builtin_amdgcn_s_barrier();
    asm volatile("s_waitcnt lgkmcnt(0)" ::: "memory");
    __builtin_amdgcn_s_setprio(1);
#pragma unroll
    for (int m = 0; m < 4; ++m)
#pragma unroll
      for (int n = 0; n < 4; ++n)
        acc[4 + m][n] = mfma16(af[m], bf[n], acc[4 + m][n]);
    __builtin_amdgcn_s_setprio(0);
    asm volatile("" ::: "memory");
    __builtin_amdgcn_s_barrier();
  }

  float bv4[4];
#pragma unroll
  for (int n = 0; n < 4; ++n) bv4[n] = bias[n0 + wc * 64 + n * 16 + cc];

  if constexpr (OUT == 2) {
#pragma unroll
    for (int n = 0; n < 4; ++n) {
      const size_t col = n0 + wc * 64 + n * 16 + cc;
#pragma unroll
      for (int m = 0; m < 8; ++m) {
        const size_t row0 = m0 + wr * 128 + m * 16 + cr * 4;
#pragma unroll
        for (int r = 0; r < 4; ++r)
          ((ushort*)Cp)[col * 16384 + row0 + r] = f2bf(acc[m][n][r] + bv4[n]);
      }
    }
  } else {
#pragma unroll
    for (int m = 0; m < 8; ++m) {
      const size_t row0 = m0 + wr * 128 + m * 16 + cr * 4;
#pragma unroll
      for (int r = 0; r < 4; ++r) {
        const size_t rowoff = (row0 + r) * N;
#pragma unroll
        for (int n = 0; n < 4; ++n) {
          const size_t col = n0 + wc * 64 + n * 16 + cc;
          const float val = acc[m][n][r] + bv4[n];
          if constexpr (OUT == 0)
            ((float*)Cp)[rowoff + col] = val;
          else
            ((ushort*)Cp)[rowoff + col] = f2bf(val);
        }
      }
    }
  }
}

// ---- GEMM (f32 A, fused cvt): BM=128, BN=256, 64 KB LDS, 2 blocks/CU -------
// One phase/tile: {8 ds_reads || publish A(k+1) (cvt+ds_write, from W-regs
// loaded at k-1) || load L-regs=A(k+2) + stage B(k+2) -> vmcnt(8/4/0) ->
// barrier -> lgkm(0) -> setprio 16 MFMA -> barrier}. Ledger: 4 vm-ops/tile
// in-order; guard vmcnt(8) retires B(k) (issued k-2). A: 2 bufs (publish k+1
// while reading k); B: 3 bufs (stage k+2). Visibility/WAR each protected by
// >=1 barrier-pair + per-wave lgkm(0) drain (same argument as the verified
// 256-tile f32a). Per-wave 64x64 out, acc=64 VGPR; launch_bounds(512,4).

template <int OUT>
__global__ __launch_bounds__(512, 4) void gemm_f32a_hi(
    const float* __restrict__ A, const ushort* __restrict__ B,
    const float* __restrict__ bias, void* __restrict__ Cp, int N, int K) {
  __shared__ __align__(16) ushort Asm2[2][4096];  // 2 x 8 KB
  __shared__ __align__(16) ushort Bsm3[3][8192];  // 3 x 16 KB
  const int tid = threadIdx.x, lane = tid & 63;
  const int wv = tid >> 6;
  const int wr = wv >> 2, wc = wv & 3;   // 2 M-waves x 4 N-waves
  const int cc = lane & 15, cr = lane >> 4;
  const int nw = N >> 8;                 // 256-col tiles
  const int work = xcd_swizzle(blockIdx.x, gridDim.x);
  const size_t m0 = (size_t)(work / nw) * 128;
  const size_t n0 = (size_t)(work % nw) * 256;

  // A staging: 512 units of 16B (128 rows x 4 slots); 1 unit/thread.
  const float* af0;
  ushort* al0;
  {
    const int row = tid >> 2, slot = tid & 3;
    af0 = A + (m0 + row) * (size_t)K + (slot ^ ((row >> 1) & 3)) * 8;
    al0 = &Asm2[0][0] + tid * 8;
  }
  // B staging: 1024 units; threads cover tid, tid+512.
  const ushort* bg[2];
#pragma unroll
  for (int h = 0; h < 2; ++h) {
    const int u = tid + h * 512;
    const int row = u >> 2, slot = u & 3;
    bg[h] = B + (n0 + row) * (size_t)K + (slot ^ ((row >> 1) & 3)) * 8;
  }

  f32x4 acc[4][4] = {};
  const int nt = K >> 5;  // 32, even

  int aoff[4], boff[4];
#pragma unroll
  for (int m = 0; m < 4; ++m) {
    const int row = wr * 64 + m * 16 + cc;
    aoff[m] = (row * 4 + (cr ^ ((row >> 1) & 3))) * 8;
  }
#pragma unroll
  for (int n = 0; n < 4; ++n) {
    const int row = wc * 64 + n * 16 + cc;
    boff[n] = (row * 4 + (cr ^ ((row >> 1) & 3))) * 8;
  }

  // prologue: A(0) -> regs -> A[0]; W = A(1); B(0),B(1) staged; drain.
  f32x4 wa0, wa1, la0, la1;
  wa0 = *(const f32x4*)(af0);      wa1 = *(const f32x4*)(af0 + 4);
  *(bf16x8*)al0 = cvt8r(wa0, wa1);
  wa0 = *(const f32x4*)(af0 + 32); wa1 = *(const f32x4*)(af0 + 36);
#pragma unroll
  for (int p = 0; p < 2; ++p) {
    gload16(bg[0] + (p << 5), &Bsm3[p][tid * 8]);
    gload16(bg[1] + (p << 5), &Bsm3[p][(tid + 512) * 8]);
  }
  asm volatile("s_waitcnt vmcnt(0) lgkmcnt(0)" ::: "memory");
  __builtin_amdgcn_s_barrier();
  asm volatile("" ::: "memory");

#define HI_TILE(k, W0, W1, L0, L1)                                            \
  {                                                                           \
    const ushort* Ab = &Asm2[(k) & 1][0];                                     \
    const ushort* Bb = &Bsm3[(k) % 3][0];                                     \
    bf16x8 bf[4], af[4];                                                      \
    _Pragma("unroll")                                                         \
    for (int n = 0; n < 4; ++n) bf[n] = *(const bf16x8*)&Bb[boff[n]];         \
    _Pragma("unroll")                                                         \
    for (int m = 0; m < 4; ++m) af[m] = *(const bf16x8*)&Ab[aoff[m]];         \
    if ((k) + 1 < nt)                                                         \
      *(bf16x8*)(al0 + (((k) + 1) & 1) * 4096) = cvt8r(W0, W1);               \
    if ((k) + 2 < nt) {                                                       \
      const int kt = ((k) + 2) << 5;                                          \
      L0 = *(const f32x4*)(af0 + kt);  L1 = *(const f32x4*)(af0 + kt + 4);    \
      gload16(bg[0] + kt, &Bsm3[((k) + 2) % 3][tid * 8]);                     \
      gload16(bg[1] + kt, &Bsm3[((k) + 2) % 3][(tid + 512) * 8]);             \
    }                                                                         \
    if ((k) < nt - 2) {                                                       \
      asm volatile("s_waitcnt vmcnt(8)" ::: "memory");                        \
    } else if ((k) == nt - 2) {                                               \
      asm volatile("s_waitcnt vmcnt(4)" ::: "memory");                        \
    } else {                                                                  \
      asm volatile("s_waitcnt vmcnt(0)" ::: "memory");                        \
    }                                                                         \
    __builtin_amdgcn_s_barrier();                                             \
    asm volatile("s_waitcnt lgkmcnt(0)" ::: "memory");                        \
    __builtin_amdgcn_s_setprio(1);                                            \
    _Pragma("unroll")                                                         \
    for (int m = 0; m < 4; ++m)                                               \
      _Pragma("unroll")                                                       \
      for (int n = 0; n < 4; ++n) acc[m][n] = mfma16(af[m], bf[n], acc[m][n]);\
    __builtin_amdgcn_s_setprio(0);                                            \
    asm volatile("" ::: "memory");                                            \
    __builtin_amdgcn_s_barrier();                                             \
  }

  for (int kk = 0; kk < nt; kk += 2) {
    HI_TILE(kk, wa0, wa1, la0, la1);       // even: publish W, load L
    HI_TILE(kk + 1, la0, la1, wa0, wa1);   // odd: publish L, load W
  }
#undef HI_TILE

  float bv4[4];
#pragma unroll
  for (int n = 0; n < 4; ++n) bv4[n] = bias[n0 + wc * 64 + n * 16 + cc];

  if constexpr (OUT == 2) {
#pragma unroll
    for (int n = 0; n < 4; ++n) {
      const size_t col = n0 + wc * 64 + n * 16 + cc;
#pragma unroll
      for (int m = 0; m < 4; ++m) {
        const size_t row0 = m0 + wr * 64 + m * 16 + cr * 4;
#pragma unroll
        for (int r = 0; r < 4; ++r)
          ((ushort*)Cp)[col * 16384 + row0 + r] = f2bf(acc[m][n][r] + bv4[n]);
      }
    }
  } else {
#pragma unroll
    for (int m = 0; m < 4; ++m) {
      const size_t row0 = m0 + wr * 64 + m * 16 + cr * 4;
#pragma unroll
      for (int r = 0; r < 4; ++r) {
        const size_t rowoff = (row0 + r) * N;
#pragma unroll
        for (int n = 0; n < 4; ++n) {
          const size_t col = n0 + wc * 64 + n * 16 + cc;
          ((ushort*)Cp)[rowoff + col] = f2bf(acc[m][n][r] + bv4[n]);
        }
      }
    }
  }
}

// ---- windowed attention: T12 swapped-QK^T (round-25 verified ~24 us) -------

__global__ __launch_bounds__(512, 4) void attn_kernel(
    const ushort* __restrict__ q, const ushort* __restrict__ k,
    const ushort* __restrict__ vt, ushort* __restrict__ x) {
  __shared__ __align__(16) ushort Ks[256 * 64];   // 32 KB
  __shared__ __align__(16) ushort Vt[64 * 256];   // 32 KB
  const int bid = blockIdx.x;
  const int w = bid & 15, h = (bid >> 4) & 15, b = bid >> 8;
  const int tid = threadIdx.x, lane = tid & 63, wv = tid >> 6;
  const int cc = lane & 15, cr = lane >> 4;
  const size_t base = ((size_t)b * 4096 + (size_t)w * 256) * 1024 + h * 64;
  const size_t vbase = ((size_t)h * 64) * 16384 + (size_t)b * 4096 + w * 256;

  const ushort* qp0 = q + base + (size_t)(wv * 32 + cc) * 1024 + cr * 8;
  const ushort* qp1 = q + base + (size_t)(wv * 32 + 16 + cc) * 1024 + cr * 8;
  const bf16x8 qA0 = *(const bf16x8*)qp0;
  const bf16x8 qA1 = *(const bf16x8*)(qp0 + 32);
  const bf16x8 qB0 = *(const bf16x8*)qp1;
  const bf16x8 qB1 = *(const bf16x8*)(qp1 + 32);

#pragma unroll
  for (int i = 0; i < 4; ++i) {
    const int u = tid + i * 512;
    const int row = u >> 3, slot = u & 7;
    gload16(k + base + (size_t)row * 1024 + ((slot ^ (row & 7)) << 3),
            &Ks[u * 8]);
  }
#pragma unroll
  for (int i = 0; i < 4; ++i) {
    const int u = tid + i * 512;
    const int dk = u >> 5, slot = u & 31;
    gload16(vt + vbase + (size_t)dk * 16384 + (((slot & 24) | ((slot ^ dk) & 7)) << 3),
            &Vt[u * 8]);
  }
  __syncthreads();

  const int s0lane = cc + (2 * (cr & 1)) * 16;
  const int s1lane = s0lane + 16;
  const bool hi = ((cr >> 1) & 1) != 0;

  for (int c = 0; c < 2; ++c) {
    const int qrow0 = wv * 32 + c * 16;
    const bf16x8 qf0 = c == 0 ? qA0 : qB0;
    const bf16x8 qf1 = c == 0 ? qA1 : qB1;

    f32x4 sc[16];
    __builtin_amdgcn_s_setprio(1);
#pragma unroll
    for (int cb = 0; cb < 16; ++cb) {
      const int row = cb * 16 + cc;
      const bf16x8 kb0 = *(const bf16x8*)&Ks[row * 64 + ((cr ^ (row & 7)) << 3)];
      const bf16x8 kb1 =
          *(const bf16x8*)&Ks[row * 64 + (((4 + cr) ^ (row & 7)) << 3)];
      f32x4 z = {0.f, 0.f, 0.f, 0.f};
      z = mfma16(kb0, qf0, z);
      z = mfma16(kb1, qf1, z);
      sc[cb] = z;
    }
    __builtin_amdgcn_s_setprio(0);

    float mx = -1e30f;
#pragma unroll
    for (int cb = 0; cb < 16; ++cb)
#pragma unroll
      for (int r = 0; r < 4; ++r) mx = fmaxf(mx, sc[cb][r]);
    mx = fmaxf(mx, __shfl_xor(mx, 16));
    mx = fmaxf(mx, __shfl_xor(mx, 32));
    float sum = 0.f;
#pragma unroll
    for (int cb = 0; cb < 16; ++cb)
#pragma unroll
      for (int r = 0; r < 4; ++r) {
        const float p = __expf((sc[cb][r] - mx) * 0.125f);
        sc[cb][r] = p;
        sum += p;
      }
    sum += __shfl_xor(sum, 16);
    sum += __shfl_xor(sum, 32);
    const float inv = 1.f / sum;

    f32x4 o[4] = {};
#pragma unroll
    for (int ks = 0; ks < 8; ++ks) {
      const unsigned p00 = cvtpk1(sc[2 * ks][0], sc[2 * ks][1]);
      const unsigned p01 = cvtpk1(sc[2 * ks][2], sc[2 * ks][3]);
      const unsigned p10 = cvtpk1(sc[2 * ks + 1][0], sc[2 * ks + 1][1]);
      const unsigned p11 = cvtpk1(sc[2 * ks + 1][2], sc[2 * ks + 1][3]);
      const unsigned a0 = (unsigned)__shfl((int)p00, s0lane);
      const unsigned b0 = (unsigned)__shfl((int)p10, s0lane);
      const unsigned a1 = (unsigned)__shfl((int)p01, s0lane);
      const unsigned b1 = (unsigned)__shfl((int)p11, s0lane);
      const unsigned a2 = (unsigned)__shfl((int)p00, s1lane);
      const unsigned b2 = (unsigned)__shfl((int)p10, s1lane);
      const unsigned a3 = (unsigned)__shfl((int)p01, s1lane);
      const unsigned b3 = (unsigned)__shfl((int)p11, s1lane);
      BF8 pf;
      pf.u[0] = hi ? b0 : a0;
      pf.u[1] = hi ? b1 : a1;
      pf.u[2] = hi ? b2 : a2;
      pf.u[3] = hi ? b3 : a3;
      __builtin_amdgcn_s_setprio(1);
#pragma unroll
      for (int db = 0; db < 4; ++db) {
        const int row = db * 16 + cc;
        const int gu = ks * 4 + cr;
        const int lu = (gu & 24) | ((gu ^ row) & 7);
        const bf16x8 bv = *(const bf16x8*)&Vt[row * 256 + lu * 8];
        o[db] = mfma16(pf.v, bv, o[db]);
      }
      __builtin_amdgcn_s_setprio(0);
    }

    float invq[4];
#pragma unroll
    for (int r = 0; r < 4; ++r) invq[r] = __shfl(inv, cr * 4 + r);

#pragma unroll
    for (int db = 0; db < 4; ++db)
#pragma unroll
      for (int r = 0; r < 4; ++r) {
        const int qr = qrow0 + cr * 4 + r;
        x[base + (size_t)qr * 1024 + db * 16 + cc] = f2bf(o[db][r] * invq[r]);
      }
  }
}

// ---- launch ----------------------------------------------------------------

extern "C" void kernel_launch(void* const* d_in, const int* in_sizes, int n_in,
                              void* d_out, int out_size, void* d_ws, size_t ws_size,
                              hipStream_t stream) {
  const float* query = (const float*)d_in[0];
  const float* key_  = (const float*)d_in[1];
  const float* value = (const float*)d_in[2];
  const float* Wq = (const float*)d_in[3];
  const float* bq = (const float*)d_in[4];
  const float* Wk = (const float*)d_in[5];
  const float* bk = (const float*)d_in[6];
  const float* Wv = (const float*)d_in[7];
  const float* bv = (const float*)d_in[8];
  const float* Wo = (const float*)d_in[9];
  const float* bo = (const float*)d_in[10];
  float* out = (float*)d_out;

  const size_t MN = (size_t)16384 * 1024;
  const size_t WN = (size_t)1024 * 1024;
  ushort* wqb = (ushort*)d_ws;
  ushort* wkb = wqb + WN;
  ushort* wvb = wkb + WN;
  ushort* wob = wvb + WN;
  ushort* qp = wob + WN;
  ushort* kp = qp + MN;
  ushort* vtp = kp + MN;   // V^T [1024][16384]

  const dim3 b256(256), b512(512);
  const dim3 ghi(512);   // (16384/128) * (1024/256)
  const dim3 g256(256);

  cvt_w<<<dim3(4 * 128), b256, 0, stream>>>(Wq, Wk, Wv, Wo, wqb, wkb, wvb, wob);

  gemm_f32a_hi<1><<<ghi, b512, 0, stream>>>(query, wqb, bq, qp, 1024, 1024);
  gemm_f32a_hi<1><<<ghi, b512, 0, stream>>>(key_,  wkb, bk, kp, 1024, 1024);
  gemm_f32a_hi<2><<<ghi, b512, 0, stream>>>(value, wvb, bv, vtp, 1024, 1024);

  attn_kernel<<<dim3(1024), b512, 0, stream>>>(qp, kp, vtp, qp /*in-place*/);

  gemm_8ph<0><<<g256, b512, 0, stream>>>(qp, wob, bo, out, 1024, 1024);
}

// Round 28
// 247.184 us; speedup vs baseline: 1.0739x; 1.0739x over previous
//
#include <hip/hip_runtime.h>
#include <hip/hip_bf16.h>

typedef __attribute__((ext_vector_type(8))) __bf16 bf16x8;
typedef __attribute__((ext_vector_type(4))) float f32x4;

#define DEVI static __device__ __forceinline__

// ---- helpers ---------------------------------------------------------------

DEVI ushort f2bf(float f) {
  unsigned u = __builtin_bit_cast(unsigned, f);
  return (ushort)((u + 0x7fffu + ((u >> 16) & 1u)) >> 16);
}

union BF8 { unsigned u[4]; bf16x8 v; };

DEVI bf16x8 cvt8(const float* __restrict__ p) {
  const f32x4 a = *(const f32x4*)p;
  const f32x4 b = *(const f32x4*)(p + 4);
  BF8 r;
  asm("v_cvt_pk_bf16_f32 %0, %1, %2" : "=v"(r.u[0]) : "v"(a.x), "v"(a.y));
  asm("v_cvt_pk_bf16_f32 %0, %1, %2" : "=v"(r.u[1]) : "v"(a.z), "v"(a.w));
  asm("v_cvt_pk_bf16_f32 %0, %1, %2" : "=v"(r.u[2]) : "v"(b.x), "v"(b.y));
  asm("v_cvt_pk_bf16_f32 %0, %1, %2" : "=v"(r.u[3]) : "v"(b.z), "v"(b.w));
  return r.v;
}

DEVI bf16x8 cvt8r(f32x4 a, f32x4 b) {
  BF8 r;
  asm("v_cvt_pk_bf16_f32 %0, %1, %2" : "=v"(r.u[0]) : "v"(a.x), "v"(a.y));
  asm("v_cvt_pk_bf16_f32 %0, %1, %2" : "=v"(r.u[1]) : "v"(a.z), "v"(a.w));
  asm("v_cvt_pk_bf16_f32 %0, %1, %2" : "=v"(r.u[2]) : "v"(b.x), "v"(b.y));
  asm("v_cvt_pk_bf16_f32 %0, %1, %2" : "=v"(r.u[3]) : "v"(b.z), "v"(b.w));
  return r.v;
}

DEVI unsigned cvtpk1(float lo, float hi) {
  unsigned r;
  asm("v_cvt_pk_bf16_f32 %0, %1, %2" : "=v"(r) : "v"(lo), "v"(hi));
  return r;
}

DEVI void gload16(const void* g, void* l) {
  __builtin_amdgcn_global_load_lds(
      (const __attribute__((address_space(1))) unsigned*)g,
      (__attribute__((address_space(3))) unsigned*)l, 16, 0, 0);
}

DEVI int xcd_swizzle(int bid, int nwg) {
  return (bid & 7) * (nwg >> 3) + (bid >> 3);
}

DEVI f32x4 mfma16(bf16x8 a, bf16x8 b, f32x4 c) {
  return __builtin_amdgcn_mfma_f32_16x16x32_bf16(a, b, c, 0, 0, 0);
}

// ---- weight convert --------------------------------------------------------

__global__ __launch_bounds__(256) void cvt_w(
    const float* __restrict__ wq, const float* __restrict__ wk,
    const float* __restrict__ wv, const float* __restrict__ wo,
    ushort* __restrict__ oq, ushort* __restrict__ ok2,
    ushort* __restrict__ ov, ushort* __restrict__ oo) {
  const int s = blockIdx.x >> 7;
  const int tb = blockIdx.x & 127;
  const float* src = s == 0 ? wq : (s == 1 ? wk : (s == 2 ? wv : wo));
  ushort* dst = s == 0 ? oq : (s == 1 ? ok2 : (s == 2 ? ov : oo));
  const unsigned G = 128 * 256;
  const unsigned t = tb * 256 + threadIdx.x;
#pragma unroll
  for (int j = 0; j < 4; ++j) {
    const size_t i = (size_t)t + (size_t)j * G;
    *(bf16x8*)(dst + i * 8) = cvt8(src + i * 8);
  }
}

// ---- GEMM (bf16 A): 256x256 tile, BK=32, 512 threads, fine-phase -----------
// Epilogue n-innermost for row-major outputs (write-combining; r26-verified
// WRITE_SIZE ideal).

template <int OUT>
__global__ __launch_bounds__(512, 2) void gemm_8ph(
    const ushort* __restrict__ A, const ushort* __restrict__ B,
    const float* __restrict__ bias, void* __restrict__ Cp, int N, int K) {
  __shared__ __align__(16) ushort Asm[4][8192];
  __shared__ __align__(16) ushort Bsm[4][8192];
  const int tid = threadIdx.x, lane = tid & 63;
  const int wv = tid >> 6;
  const int wr = wv >> 2, wc = wv & 3;
  const int cc = lane & 15, cr = lane >> 4;
  const int nw = N >> 8;
  const int work = xcd_swizzle(blockIdx.x, gridDim.x);
  const size_t m0 = (size_t)(work / nw) * 256;
  const size_t n0 = (size_t)(work % nw) * 256;

  const ushort *ag[2], *bg[2];
#pragma unroll
  for (int h = 0; h < 2; ++h) {
    const int u = tid + h * 512;
    const int row = u >> 2, slot = u & 3;
    const int gc = (slot ^ ((row >> 1) & 3)) * 8;
    ag[h] = A + (m0 + row) * (size_t)K + gc;
    bg[h] = B + (n0 + row) * (size_t)K + gc;
  }

  auto stageh = [&](int buf, int kt, int h) {
    gload16(ag[h] + kt, &Asm[buf][(tid + h * 512) * 8]);
    gload16(bg[h] + kt, &Bsm[buf][(tid + h * 512) * 8]);
  };

  f32x4 acc[8][4] = {};
  const int nt = K >> 5;

  int aoff[8], boff[4];
#pragma unroll
  for (int m = 0; m < 8; ++m) {
    const int row = wr * 128 + m * 16 + cc;
    aoff[m] = (row * 4 + (cr ^ ((row >> 1) & 3))) * 8;
  }
#pragma unroll
  for (int n = 0; n < 4; ++n) {
    const int row = wc * 64 + n * 16 + cc;
    boff[n] = (row * 4 + (cr ^ ((row >> 1) & 3))) * 8;
  }

#pragma unroll
  for (int p = 0; p < 3; ++p) {
    stageh(p, p << 5, 0);
    stageh(p, p << 5, 1);
  }
  asm volatile("s_waitcnt vmcnt(8)" ::: "memory");
  __builtin_amdgcn_s_barrier();
  asm volatile("" ::: "memory");

  for (int k = 0; k < nt; ++k) {
    const ushort* Ab = Asm[k & 3];
    const ushort* Bb = Bsm[k & 3];
    const int wb = (k + 3) & 3;
    const bool more = (k + 3 < nt);
    bf16x8 bf[4], af[4];

#pragma unroll
    for (int n = 0; n < 4; ++n) bf[n] = *(const bf16x8*)&Bb[boff[n]];
#pragma unroll
    for (int m = 0; m < 4; ++m) af[m] = *(const bf16x8*)&Ab[aoff[m]];
    if (more) stageh(wb, (k + 3) << 5, 0);
    __builtin_amdgcn_s_barrier();
    asm volatile("s_waitcnt lgkmcnt(0)" ::: "memory");
    __builtin_amdgcn_s_setprio(1);
#pragma unroll
    for (int m = 0; m < 4; ++m)
#pragma unroll
      for (int n = 0; n < 4; ++n)
        acc[m][n] = mfma16(af[m], bf[n], acc[m][n]);
    __builtin_amdgcn_s_setprio(0);
    asm volatile("" ::: "memory");
    __builtin_amdgcn_s_barrier();

#pragma unroll
    for (int m = 0; m < 4; ++m) af[m] = *(const bf16x8*)&Ab[aoff[4 + m]];
    if (more) stageh(wb, (k + 3) << 5, 1);
    if (k < nt - 3) {
      asm volatile("s_waitcnt vmcnt(8)" ::: "memory");
    } else if (k == nt - 3) {
      asm volatile("s_waitcnt vmcnt(4)" ::: "memory");
    } else if (k == nt - 2) {
      asm volatile("s_waitcnt vmcnt(0)" ::: "memory");
    }
    __builtin_amdgcn_s_barrier();
    asm volatile("s_waitcnt lgkmcnt(0)" ::: "memory");
    __builtin_amdgcn_s_setprio(1);
#pragma unroll
    for (int m = 0; m < 4; ++m)
#pragma unroll
      for (int n = 0; n < 4; ++n)
        acc[4 + m][n] = mfma16(af[m], bf[n], acc[4 + m][n]);
    __builtin_amdgcn_s_setprio(0);
    asm volatile("" ::: "memory");
    __builtin_amdgcn_s_barrier();
  }

  float bv4[4];
#pragma unroll
  for (int n = 0; n < 4; ++n) bv4[n] = bias[n0 + wc * 64 + n * 16 + cc];

  if constexpr (OUT == 2) {
#pragma unroll
    for (int n = 0; n < 4; ++n) {
      const size_t col = n0 + wc * 64 + n * 16 + cc;
#pragma unroll
      for (int m = 0; m < 8; ++m) {
        const size_t row0 = m0 + wr * 128 + m * 16 + cr * 4;
#pragma unroll
        for (int r = 0; r < 4; ++r)
          ((ushort*)Cp)[col * 16384 + row0 + r] = f2bf(acc[m][n][r] + bv4[n]);
      }
    }
  } else {
#pragma unroll
    for (int m = 0; m < 8; ++m) {
      const size_t row0 = m0 + wr * 128 + m * 16 + cr * 4;
#pragma unroll
      for (int r = 0; r < 4; ++r) {
        const size_t rowoff = (row0 + r) * N;
#pragma unroll
        for (int n = 0; n < 4; ++n) {
          const size_t col = n0 + wc * 64 + n * 16 + cc;
          const float val = acc[m][n][r] + bv4[n];
          if constexpr (OUT == 0)
            ((float*)Cp)[rowoff + col] = val;
          else
            ((ushort*)Cp)[rowoff + col] = f2bf(val);
        }
      }
    }
  }
}

// ---- GEMM (f32 A, fused cvt, ph0 publish, n-innermost epilogue) ------------
// r26-verified: 62 us/dispatch, WRITE_SIZE ideal.

template <int OUT>
__global__ __launch_bounds__(512, 2) void gemm_8ph_f32a(
    const float* __restrict__ A, const ushort* __restrict__ B,
    const float* __restrict__ bias, void* __restrict__ Cp, int N, int K) {
  __shared__ __align__(16) ushort Asm[4][8192];
  __shared__ __align__(16) ushort Bsm[4][8192];
  const int tid = threadIdx.x, lane = tid & 63;
  const int wv = tid >> 6;
  const int wr = wv >> 2, wc = wv & 3;
  const int cc = lane & 15, cr = lane >> 4;
  const int nw = N >> 8;
  const int work = xcd_swizzle(blockIdx.x, gridDim.x);
  const size_t m0 = (size_t)(work / nw) * 256;
  const size_t n0 = (size_t)(work % nw) * 256;

  const float *af0, *af1;
  ushort *al0, *al1;
  {
    const int u0 = tid, r0 = u0 >> 2, s0 = u0 & 3;
    const int u1 = tid + 512, r1 = u1 >> 2, s1 = u1 & 3;
    af0 = A + (m0 + r0) * (size_t)K + (s0 ^ ((r0 >> 1) & 3)) * 8;
    af1 = A + (m0 + r1) * (size_t)K + (s1 ^ ((r1 >> 1) & 3)) * 8;
    al0 = &Asm[0][0] + u0 * 8;
    al1 = &Asm[0][0] + u1 * 8;
  }
  const ushort* bg[2];
#pragma unroll
  for (int h = 0; h < 2; ++h) {
    const int u = tid + h * 512;
    const int row = u >> 2, slot = u & 3;
    bg[h] = B + (n0 + row) * (size_t)K + (slot ^ ((row >> 1) & 3)) * 8;
  }

  f32x4 acc[8][4] = {};
  const int nt = K >> 5;

  int aoff[8], boff[4];
#pragma unroll
  for (int m = 0; m < 8; ++m) {
    const int row = wr * 128 + m * 16 + cc;
    aoff[m] = (row * 4 + (cr ^ ((row >> 1) & 3))) * 8;
  }
#pragma unroll
  for (int n = 0; n < 4; ++n) {
    const int row = wc * 64 + n * 16 + cc;
    boff[n] = (row * 4 + (cr ^ ((row >> 1) & 3))) * 8;
  }

  f32x4 sa0, sa1, sa2, sa3, sb0, sb1, sb2, sb3;
#pragma unroll
  for (int p = 0; p < 2; ++p) {
    const int kt = p << 5;
    sa0 = *(const f32x4*)(af0 + kt);  sa1 = *(const f32x4*)(af0 + kt + 4);
    sa2 = *(const f32x4*)(af1 + kt);  sa3 = *(const f32x4*)(af1 + kt + 4);
    *(bf16x8*)(al0 + p * 8192) = cvt8r(sa0, sa1);
    *(bf16x8*)(al1 + p * 8192) = cvt8r(sa2, sa3);
  }
  sa0 = *(const f32x4*)(af0 + 64);  sa1 = *(const f32x4*)(af0 + 68);
  sa2 = *(const f32x4*)(af1 + 64);  sa3 = *(const f32x4*)(af1 + 68);
#pragma unroll
  for (int p = 0; p < 3; ++p) {
    gload16(bg[0] + (p << 5), &Bsm[p][tid * 8]);
    gload16(bg[1] + (p << 5), &Bsm[p][(tid + 512) * 8]);
  }
  asm volatile("s_waitcnt vmcnt(0) lgkmcnt(0)" ::: "memory");
  __builtin_amdgcn_s_barrier();
  asm volatile("" ::: "memory");

#define F32A_TILE(k, W0, W1, W2, W3, L0, L1, L2, L3)                          \
  {                                                                           \
    const ushort* Ab = Asm[(k) & 3];                                          \
    const ushort* Bb = Bsm[(k) & 3];                                          \
    const int wb = ((k) + 3) & 3;                                             \
    const bool more = ((k) + 3 < nt);                                         \
    bf16x8 bf[4], af[4];                                                      \
    _Pragma("unroll")                                                         \
    for (int n = 0; n < 4; ++n) bf[n] = *(const bf16x8*)&Bb[boff[n]];         \
    _Pragma("unroll")                                                         \
    for (int m = 0; m < 4; ++m) af[m] = *(const bf16x8*)&Ab[aoff[m]];         \
    if ((k) + 2 < nt) {                                                       \
      const int wbuf = ((k) + 2) & 3;                                         \
      *(bf16x8*)(al0 + wbuf * 8192) = cvt8r(W0, W1);                          \
      *(bf16x8*)(al1 + wbuf * 8192) = cvt8r(W2, W3);                          \
    }                                                                         \
    if (more) {                                                               \
      const int kt = ((k) + 3) << 5;                                          \
      L0 = *(const f32x4*)(af0 + kt);  L1 = *(const f32x4*)(af0 + kt + 4);    \
      L2 = *(const f32x4*)(af1 + kt);  L3 = *(const f32x4*)(af1 + kt + 4);    \
      gload16(bg[0] + kt, &Bsm[wb][tid * 8]);                                 \
    }                                                                         \
    if ((k) < nt - 3) {                                                       \
      asm volatile("s_waitcnt vmcnt(17)" ::: "memory");                       \
    } else if ((k) == nt - 3) {                                               \
      asm volatile("s_waitcnt vmcnt(12)" ::: "memory");                       \
    } else if ((k) == nt - 2) {                                               \
      asm volatile("s_waitcnt vmcnt(6)" ::: "memory");                        \
    } else {                                                                  \
      asm volatile("s_waitcnt vmcnt(0)" ::: "memory");                        \
    }                                                                         \
    __builtin_amdgcn_s_barrier();                                             \
    asm volatile("s_waitcnt lgkmcnt(0)" ::: "memory");                        \
    __builtin_amdgcn_s_setprio(1);                                            \
    _Pragma("unroll")                                                         \
    for (int m = 0; m < 4; ++m)                                               \
      _Pragma("unroll")                                                       \
      for (int n = 0; n < 4; ++n) acc[m][n] = mfma16(af[m], bf[n], acc[m][n]);\
    __builtin_amdgcn_s_setprio(0);                                            \
    asm volatile("" ::: "memory");                                            \
    __builtin_amdgcn_s_barrier();                                             \
    _Pragma("unroll")                                                         \
    for (int m = 0; m < 4; ++m) af[m] = *(const bf16x8*)&Ab[aoff[4 + m]];     \
    if (more) gload16(bg[1] + (((k) + 3) << 5), &Bsm[wb][(tid + 512) * 8]);   \
    __builtin_amdgcn_s_barrier();                                             \
    asm volatile("s_waitcnt lgkmcnt(0)" ::: "memory");                        \
    __builtin_amdgcn_s_setprio(1);                                            \
    _Pragma("unroll")                                                         \
    for (int m = 0; m < 4; ++m)                                               \
      _Pragma("unroll")                                                       \
      for (int n = 0; n < 4; ++n)                                             \
        acc[4 + m][n] = mfma16(af[m], bf[n], acc[4 + m][n]);                  \
    __builtin_amdgcn_s_setprio(0);                                            \
    asm volatile("" ::: "memory");                                            \
    __builtin_amdgcn_s_barrier();                                             \
  }

  for (int kk = 0; kk < nt; kk += 2) {
    F32A_TILE(kk, sa0, sa1, sa2, sa3, sb0, sb1, sb2, sb3);
    F32A_TILE(kk + 1, sb0, sb1, sb2, sb3, sa0, sa1, sa2, sa3);
  }
#undef F32A_TILE

  float bv4[4];
#pragma unroll
  for (int n = 0; n < 4; ++n) bv4[n] = bias[n0 + wc * 64 + n * 16 + cc];

  if constexpr (OUT == 2) {
#pragma unroll
    for (int n = 0; n < 4; ++n) {
      const size_t col = n0 + wc * 64 + n * 16 + cc;
#pragma unroll
      for (int m = 0; m < 8; ++m) {
        const size_t row0 = m0 + wr * 128 + m * 16 + cr * 4;
#pragma unroll
        for (int r = 0; r < 4; ++r)
          ((ushort*)Cp)[col * 16384 + row0 + r] = f2bf(acc[m][n][r] + bv4[n]);
      }
    }
  } else {
#pragma unroll
    for (int m = 0; m < 8; ++m) {
      const size_t row0 = m0 + wr * 128 + m * 16 + cr * 4;
#pragma unroll
      for (int r = 0; r < 4; ++r) {
        const size_t rowoff = (row0 + r) * N;
#pragma unroll
        for (int n = 0; n < 4; ++n) {
          const size_t col = n0 + wc * 64 + n * 16 + cc;
          ((ushort*)Cp)[rowoff + col] = f2bf(acc[m][n][r] + bv4[n]);
        }
      }
    }
  }
}

// ---- windowed attention: T12 swapped-QK^T (r25-verified ~24 us) ------------

__global__ __launch_bounds__(512, 4) void attn_kernel(
    const ushort* __restrict__ q, const ushort* __restrict__ k,
    const ushort* __restrict__ vt, ushort* __restrict__ x) {
  __shared__ __align__(16) ushort Ks[256 * 64];   // 32 KB
  __shared__ __align__(16) ushort Vt[64 * 256];   // 32 KB
  const int bid = blockIdx.x;
  const int w = bid & 15, h = (bid >> 4) & 15, b = bid >> 8;
  const int tid = threadIdx.x, lane = tid & 63, wv = tid >> 6;
  const int cc = lane & 15, cr = lane >> 4;
  const size_t base = ((size_t)b * 4096 + (size_t)w * 256) * 1024 + h * 64;
  const size_t vbase = ((size_t)h * 64) * 16384 + (size_t)b * 4096 + w * 256;

  const ushort* qp0 = q + base + (size_t)(wv * 32 + cc) * 1024 + cr * 8;
  const ushort* qp1 = q + base + (size_t)(wv * 32 + 16 + cc) * 1024 + cr * 8;
  const bf16x8 qA0 = *(const bf16x8*)qp0;
  const bf16x8 qA1 = *(const bf16x8*)(qp0 + 32);
  const bf16x8 qB0 = *(const bf16x8*)qp1;
  const bf16x8 qB1 = *(const bf16x8*)(qp1 + 32);

#pragma unroll
  for (int i = 0; i < 4; ++i) {
    const int u = tid + i * 512;
    const int row = u >> 3, slot = u & 7;
    gload16(k + base + (size_t)row * 1024 + ((slot ^ (row & 7)) << 3),
            &Ks[u * 8]);
  }
#pragma unroll
  for (int i = 0; i < 4; ++i) {
    const int u = tid + i * 512;
    const int dk = u >> 5, slot = u & 31;
    gload16(vt + vbase + (size_t)dk * 16384 + (((slot & 24) | ((slot ^ dk) & 7)) << 3),
            &Vt[u * 8]);
  }
  __syncthreads();

  const int s0lane = cc + (2 * (cr & 1)) * 16;
  const int s1lane = s0lane + 16;
  const bool hi = ((cr >> 1) & 1) != 0;

  for (int c = 0; c < 2; ++c) {
    const int qrow0 = wv * 32 + c * 16;
    const bf16x8 qf0 = c == 0 ? qA0 : qB0;
    const bf16x8 qf1 = c == 0 ? qA1 : qB1;

    f32x4 sc[16];
    __builtin_amdgcn_s_setprio(1);
#pragma unroll
    for (int cb = 0; cb < 16; ++cb) {
      const int row = cb * 16 + cc;
      const bf16x8 kb0 = *(const bf16x8*)&Ks[row * 64 + ((cr ^ (row & 7)) << 3)];
      const bf16x8 kb1 =
          *(const bf16x8*)&Ks[row * 64 + (((4 + cr) ^ (row & 7)) << 3)];
      f32x4 z = {0.f, 0.f, 0.f, 0.f};
      z = mfma16(kb0, qf0, z);
      z = mfma16(kb1, qf1, z);
      sc[cb] = z;
    }
    __builtin_amdgcn_s_setprio(0);

    float mx = -1e30f;
#pragma unroll
    for (int cb = 0; cb < 16; ++cb)
#pragma unroll
      for (int r = 0; r < 4; ++r) mx = fmaxf(mx, sc[cb][r]);
    mx = fmaxf(mx, __shfl_xor(mx, 16));
    mx = fmaxf(mx, __shfl_xor(mx, 32));
    float sum = 0.f;
#pragma unroll
    for (int cb = 0; cb < 16; ++cb)
#pragma unroll
      for (int r = 0; r < 4; ++r) {
        const float p = __expf((sc[cb][r] - mx) * 0.125f);
        sc[cb][r] = p;
        sum += p;
      }
    sum += __shfl_xor(sum, 16);
    sum += __shfl_xor(sum, 32);
    const float inv = 1.f / sum;

    f32x4 o[4] = {};
#pragma unroll
    for (int ks = 0; ks < 8; ++ks) {
      const unsigned p00 = cvtpk1(sc[2 * ks][0], sc[2 * ks][1]);
      const unsigned p01 = cvtpk1(sc[2 * ks][2], sc[2 * ks][3]);
      const unsigned p10 = cvtpk1(sc[2 * ks + 1][0], sc[2 * ks + 1][1]);
      const unsigned p11 = cvtpk1(sc[2 * ks + 1][2], sc[2 * ks + 1][3]);
      const unsigned a0 = (unsigned)__shfl((int)p00, s0lane);
      const unsigned b0 = (unsigned)__shfl((int)p10, s0lane);
      const unsigned a1 = (unsigned)__shfl((int)p01, s0lane);
      const unsigned b1 = (unsigned)__shfl((int)p11, s0lane);
      const unsigned a2 = (unsigned)__shfl((int)p00, s1lane);
      const unsigned b2 = (unsigned)__shfl((int)p10, s1lane);
      const unsigned a3 = (unsigned)__shfl((int)p01, s1lane);
      const unsigned b3 = (unsigned)__shfl((int)p11, s1lane);
      BF8 pf;
      pf.u[0] = hi ? b0 : a0;
      pf.u[1] = hi ? b1 : a1;
      pf.u[2] = hi ? b2 : a2;
      pf.u[3] = hi ? b3 : a3;
      __builtin_amdgcn_s_setprio(1);
#pragma unroll
      for (int db = 0; db < 4; ++db) {
        const int row = db * 16 + cc;
        const int gu = ks * 4 + cr;
        const int lu = (gu & 24) | ((gu ^ row) & 7);
        const bf16x8 bv = *(const bf16x8*)&Vt[row * 256 + lu * 8];
        o[db] = mfma16(pf.v, bv, o[db]);
      }
      __builtin_amdgcn_s_setprio(0);
    }

    float invq[4];
#pragma unroll
    for (int r = 0; r < 4; ++r) invq[r] = __shfl(inv, cr * 4 + r);

#pragma unroll
    for (int db = 0; db < 4; ++db)
#pragma unroll
      for (int r = 0; r < 4; ++r) {
        const int qr = qrow0 + cr * 4 + r;
        x[base + (size_t)qr * 1024 + db * 16 + cc] = f2bf(o[db][r] * invq[r]);
      }
  }
}

// ---- launch ----------------------------------------------------------------

extern "C" void kernel_launch(void* const* d_in, const int* in_sizes, int n_in,
                              void* d_out, int out_size, void* d_ws, size_t ws_size,
                              hipStream_t stream) {
  const float* query = (const float*)d_in[0];
  const float* key_  = (const float*)d_in[1];
  const float* value = (const float*)d_in[2];
  const float* Wq = (const float*)d_in[3];
  const float* bq = (const float*)d_in[4];
  const float* Wk = (const float*)d_in[5];
  const float* bk = (const float*)d_in[6];
  const float* Wv = (const float*)d_in[7];
  const float* bv = (const float*)d_in[8];
  const float* Wo = (const float*)d_in[9];
  const float* bo = (const float*)d_in[10];
  float* out = (float*)d_out;

  const size_t MN = (size_t)16384 * 1024;
  const size_t WN = (size_t)1024 * 1024;
  ushort* wqb = (ushort*)d_ws;
  ushort* wkb = wqb + WN;
  ushort* wvb = wkb + WN;
  ushort* wob = wvb + WN;
  ushort* qp = wob + WN;
  ushort* kp = qp + MN;
  ushort* vtp = kp + MN;   // V^T [1024][16384]

  const dim3 b256(256), b512(512);
  const dim3 ggrid(256);

  cvt_w<<<dim3(4 * 128), b256, 0, stream>>>(Wq, Wk, Wv, Wo, wqb, wkb, wvb, wob);

  gemm_8ph_f32a<1><<<ggrid, b512, 0, stream>>>(query, wqb, bq, qp, 1024, 1024);
  gemm_8ph_f32a<1><<<ggrid, b512, 0, stream>>>(key_,  wkb, bk, kp, 1024, 1024);
  gemm_8ph_f32a<2><<<ggrid, b512, 0, stream>>>(value, wvb, bv, vtp, 1024, 1024);

  attn_kernel<<<dim3(1024), b512, 0, stream>>>(qp, kp, vtp, qp /*in-place*/);

  gemm_8ph<0><<<ggrid, b512, 0, stream>>>(qp, wob, bo, out, 1024, 1024);
}